// Round 18
// baseline (2822.427 us; speedup 1.0000x reference)
//
#include <hip/hip_runtime.h>
#include <cstdint>
#include <cstddef>

typedef _Float16 f16;
typedef _Float16 f16x8 __attribute__((ext_vector_type(8)));
typedef _Float16 f16x2 __attribute__((ext_vector_type(2)));
typedef float f32x4 __attribute__((ext_vector_type(4)));

#define B_ 64
#define I_ 128
#define H_ 256
#define T_ 1024
#define BT_ (B_*T_)

// ---------- helpers ----------
__device__ __forceinline__ uint32_t pack2_f16(float a, float b) {
  union { f16 h; uint16_t u; } ua, ub;
  ua.h = (f16)a; ub.h = (f16)b;
  return ((uint32_t)ub.u << 16) | (uint32_t)ua.u;
}

__device__ __forceinline__ float fdot2_u(uint32_t w, uint32_t x, float acc) {
  union { uint32_t u; f16x2 h; } uw, ux;
  uw.u = w; ux.u = x;
  return __builtin_amdgcn_fdot2(uw.h, ux.h, acc, false);
}

__device__ __forceinline__ float tanh_stable(float s) {
  float a = fabsf(s);
  float e = __expf(-2.f * a);
  float t = (1.f - e) * __fdividef(1.f, 1.f + e);
  return s < 0.f ? -t : t;
}

__device__ __forceinline__ float sigmoidf(float s) {
  return __fdividef(1.f, 1.f + __expf(-s));
}

// Barrier with LDS-visibility only (ds ops drained via lgkmcnt; vmcnt loads
// stay in flight). Correct for our use: only LDS data (rhdh/hdh) crosses it.
__device__ __forceinline__ void bar_lgkm() {
  __builtin_amdgcn_sched_barrier(0);
  asm volatile("s_waitcnt lgkmcnt(0)" ::: "memory");
  __builtin_amdgcn_s_barrier();
  __builtin_amdgcn_sched_barrier(0);
}

// MFMA fragment load (verified R3==R4)
__device__ __forceinline__ f16x8 load_frag(const f16* row, int k0, int g4) {
  union { uint32_t u[4]; f16x8 h; } r;
  const uint32_t* p0 = (const uint32_t*)(row + k0 + g4);
  const uint32_t* p1 = (const uint32_t*)(row + k0 + 16 + g4);
  r.u[0] = p0[0]; r.u[1] = p0[1];
  r.u[2] = p1[0]; r.u[3] = p1[1];
  return r.h;
}

// ---------- K0: transpose Delta [B,I,T] -> Dt f16 [B,T,I] ----------
__global__ void k_transpose_d(const float* __restrict__ D, f16* __restrict__ Dt) {
  __shared__ float tile[64][65];
  int t0 = blockIdx.x * 64, i0 = blockIdx.y * 64, b = blockIdx.z;
  int tx = threadIdx.x, ty = threadIdx.y;  // 64 x 4
  #pragma unroll
  for (int r = 0; r < 16; ++r) {
    int il = ty + r * 4;
    tile[il][tx] = D[((size_t)(b * I_ + i0 + il)) * T_ + t0 + tx];
  }
  __syncthreads();
  #pragma unroll
  for (int r = 0; r < 16; ++r) {
    int tl = ty + r * 4;
    Dt[((size_t)(b * T_ + t0 + tl)) * I_ + i0 + tx] = (f16)tile[tx][tl];
  }
}

// ---------- K_w: weight prep for quad-shuffle recurrence ----------
// Lane map: t<512: w=t>>6, l=t&63, rloc=l>>2, ks=l&3; row(p)=w*16+rloc+p*128.
// blobR  [c<64][t]:  c=p*32+cc -> Whr[row(p)][ks*64+2cc] pair.      (regs)
// blobHrg[c<56][t]:  c=p*28+cc -> Whh[row(p)][ks*64+2cc] (cc<28).   (regs)
// blobHl [j<2][t] uint4: q<4 -> Whh[row(j)][ks*64+56+2q] pair.      (LDS)
// blobZ  [c4<16][t] uint4: c4=p*8+qq, q<4 -> Whz[row(p)][ks*64+qq*8+2q]. (LDS)
__global__ void k_prep(const float* __restrict__ Wdgx, const float* __restrict__ bdgx,
                       const float* __restrict__ Wdgh, const float* __restrict__ bdgh,
                       const float* __restrict__ Wxz, const float* __restrict__ Whz,
                       const float* __restrict__ Wmz, const float* __restrict__ bmz,
                       const float* __restrict__ Wxr, const float* __restrict__ Whr,
                       const float* __restrict__ Wmr,
                       const float* __restrict__ Wxh, const float* __restrict__ Whh,
                       const float* __restrict__ Wmh, const float* __restrict__ bmh,
                       f16* __restrict__ Wg, float* __restrict__ bg,
                       f16* __restrict__ W3, float* __restrict__ b3,
                       uint32_t* __restrict__ blobR, uint32_t* __restrict__ blobHrg,
                       uint32_t* __restrict__ blobZ4, uint32_t* __restrict__ blobHl4) {
  int tid = blockIdx.x * blockDim.x + threadIdx.x;
  int nth = gridDim.x * blockDim.x;
  for (int idx = tid; idx < 384 * 128; idx += nth) {
    int j = idx >> 7, k = idx & 127;
    float v = (j < 128) ? Wdgx[j * 128 + k] : Wdgh[(j - 128) * 128 + k];
    Wg[idx] = (f16)v;
  }
  for (int j = tid; j < 384; j += nth) bg[j] = (j < 128) ? bdgx[j] : bdgh[j - 128];
  for (int idx = tid; idx < 768 * 256; idx += nth) {
    int j = idx >> 8, c = idx & 255;
    const float* Wx = (j < 256) ? Wxz : ((j < 512) ? Wxr : Wxh);
    const float* Wm = (j < 256) ? Wmz : ((j < 512) ? Wmr : Wmh);
    int jj = j & 255;
    float v = (c < 128) ? Wx[jj * 128 + c] : Wm[jj * 128 + (c - 128)];
    W3[idx] = (f16)v;
  }
  for (int j = tid; j < 768; j += nth)
    b3[j] = (j < 256) ? bmz[j] : ((j < 512) ? 0.0f : bmh[j - 512]);
  // blobR
  for (int idx = tid; idx < 64 * 512; idx += nth) {
    int c = idx >> 9, t = idx & 511;
    int p = c >> 5, cc = c & 31;
    int w = t >> 6, l = t & 63, rloc = l >> 2, ks = l & 3;
    int row = w * 16 + rloc + p * 128;
    int k = ks * 64 + cc * 2;
    blobR[idx] = pack2_f16(Whr[row * 256 + k], Whr[row * 256 + k + 1]);
  }
  // blobHrg
  for (int idx = tid; idx < 56 * 512; idx += nth) {
    int c = idx >> 9, t = idx & 511;
    int p = (c >= 28) ? 1 : 0, cc = c - p * 28;
    int w = t >> 6, l = t & 63, rloc = l >> 2, ks = l & 3;
    int row = w * 16 + rloc + p * 128;
    int k = ks * 64 + cc * 2;
    blobHrg[idx] = pack2_f16(Whh[row * 256 + k], Whh[row * 256 + k + 1]);
  }
  // blobZ4
  for (int idx = tid; idx < 16 * 512 * 4; idx += nth) {
    int q = idx & 3, r = idx >> 2;
    int t = r & 511, c4 = r >> 9;
    int p = c4 >> 3, qq = c4 & 7;
    int w = t >> 6, l = t & 63, rloc = l >> 2, ks = l & 3;
    int row = w * 16 + rloc + p * 128;
    int k = ks * 64 + qq * 8 + q * 2;
    blobZ4[idx] = pack2_f16(Whz[row * 256 + k], Whz[row * 256 + k + 1]);
  }
  // blobHl4
  for (int idx = tid; idx < 2 * 512 * 4; idx += nth) {
    int q = idx & 3, r = idx >> 2;
    int t = r & 511, p = r >> 9;
    int w = t >> 6, l = t & 63, rloc = l >> 2, ks = l & 3;
    int row = w * 16 + rloc + p * 128;
    int k = ks * 64 + 56 + q * 2;
    blobHl4[idx] = pack2_f16(Whh[row * 256 + k], Whh[row * 256 + k + 1]);
  }
}

// ---------- K1 (MFMA): Gx/Gh = exp(-relu(Dt @ Wg^T + bg)) ----------
__global__ __launch_bounds__(256) void k_gemm1(const f16* __restrict__ A,
                                               const f16* __restrict__ W,
                                               const float* __restrict__ bias,
                                               float* __restrict__ Gx,
                                               f16* __restrict__ Gh) {
  __shared__ __align__(16) f16 As[64][136];
  __shared__ __align__(16) f16 Ws[128][136];
  int m0 = blockIdx.x * 64, n0 = blockIdx.y * 128;
  int tid = threadIdx.x;
  {
    int r = tid >> 2, sgm = tid & 3;
    const uint4* src = (const uint4*)(A + (size_t)(m0 + r) * 128 + sgm * 32);
    uint4* dst = (uint4*)(&As[r][sgm * 32]);
    #pragma unroll
    for (int q = 0; q < 4; ++q) dst[q] = src[q];
  }
  {
    int r = tid >> 1, hf = tid & 1;
    const uint4* src = (const uint4*)(W + (size_t)(n0 + r) * 128 + hf * 64);
    uint4* dst = (uint4*)(&Ws[r][hf * 64]);
    #pragma unroll
    for (int q = 0; q < 8; ++q) dst[q] = src[q];
  }
  __syncthreads();
  int w = tid >> 6, l = tid & 63;
  int lr = l & 15, g4 = (l >> 4) * 4;
  f32x4 acc[8] = {};
  #pragma unroll
  for (int kk = 0; kk < 4; ++kk) {
    int k0 = kk * 32;
    f16x8 a = load_frag(&As[w * 16 + lr][0], k0, g4);
    #pragma unroll
    for (int nt = 0; nt < 8; ++nt) {
      f16x8 bf = load_frag(&Ws[nt * 16 + lr][0], k0, g4);
      acc[nt] = __builtin_amdgcn_mfma_f32_16x16x32_f16(a, bf, acc[nt], 0, 0, 0);
    }
  }
  int row4 = (l >> 4) * 4;
  #pragma unroll
  for (int nt = 0; nt < 8; ++nt) {
    int n = n0 + nt * 16 + lr;
    float bv = bias[n];
    #pragma unroll
    for (int reg = 0; reg < 4; ++reg) {
      int m = m0 + w * 16 + row4 + reg;
      float s = acc[nt][reg] + bv;
      float g = __expf(-fmaxf(s, 0.0f));
      if (n < 128) Gx[(size_t)m * 128 + n] = g;
      else         Gh[(size_t)m * 256 + (n - 128)] = (f16)g;
    }
  }
}

// ---------- K3 (MFMA): P = AC @ W3^T + b3 (f16 out) ----------
__global__ __launch_bounds__(256) void k_gemm3(const f16* __restrict__ A,
                                               const f16* __restrict__ W,
                                               const float* __restrict__ bias,
                                               f16* __restrict__ P) {
  __shared__ __align__(16) f16 As[64][136];
  __shared__ __align__(16) f16 Ws[128][136];
  int m0 = blockIdx.x * 64, n0 = blockIdx.y * 128;
  int tid = threadIdx.x;
  int w = tid >> 6, l = tid & 63, lr = l & 15, g4 = (l >> 4) * 4;
  f32x4 acc[8] = {};
  for (int kh = 0; kh < 2; ++kh) {
    {
      int r = tid >> 2, sgm = tid & 3;
      const uint4* src = (const uint4*)(A + (size_t)(m0 + r) * 256 + kh * 128 + sgm * 32);
      uint4* dst = (uint4*)(&As[r][sgm * 32]);
      #pragma unroll
      for (int q = 0; q < 4; ++q) dst[q] = src[q];
    }
    {
      int r = tid >> 1, hf = tid & 1;
      const uint4* src = (const uint4*)(W + (size_t)(n0 + r) * 256 + kh * 128 + hf * 64);
      uint4* dst = (uint4*)(&Ws[r][hf * 64]);
      #pragma unroll
      for (int q = 0; q < 8; ++q) dst[q] = src[q];
    }
    __syncthreads();
    #pragma unroll
    for (int kk = 0; kk < 4; ++kk) {
      int k0 = kk * 32;
      f16x8 a = load_frag(&As[w * 16 + lr][0], k0, g4);
      #pragma unroll
      for (int nt = 0; nt < 8; ++nt) {
        f16x8 bf = load_frag(&Ws[nt * 16 + lr][0], k0, g4);
        acc[nt] = __builtin_amdgcn_mfma_f32_16x16x32_f16(a, bf, acc[nt], 0, 0, 0);
      }
    }
    __syncthreads();
  }
  int row4 = (l >> 4) * 4;
  #pragma unroll
  for (int nt = 0; nt < 8; ++nt) {
    int n = n0 + nt * 16 + lr;
    float bv = bias[n];
    #pragma unroll
    for (int reg = 0; reg < 4; ++reg) {
      int m = m0 + w * 16 + row4 + reg;
      P[(size_t)m * 768 + n] = (f16)(acc[nt][reg] + bv);
    }
  }
}

// ---------- K2a: per-segment last-observation summaries ----------
__global__ void k_seg(const float* __restrict__ X, const float* __restrict__ M,
                      float* __restrict__ segX, float* __restrict__ segF) {
  int b = blockIdx.x, s = blockIdx.y, i = threadIdx.x;
  const float* xr = X + ((size_t)(b * I_ + i)) * T_ + s * 128;
  const float* mr = M + ((size_t)(b * I_ + i)) * T_ + s * 128;
  float last = 0.f, seen = 0.f;
  for (int t = 0; t < 128; ++t) {
    float m = mr[t];
    float x = xr[t];
    if (m > 0.f) { last = x; seen = 1.f; }
  }
  segX[((size_t)(b * I_ + i)) * 8 + s] = last;
  segF[((size_t)(b * I_ + i)) * 8 + s] = seen;
}

// ---------- K2b: x_last + double imputation -> AC f16 [BT][256] = [x2 | m] ----------
__global__ void k_x2(const float* __restrict__ X, const float* __restrict__ M,
                     const float* __restrict__ Gx, const float* __restrict__ xmean_p,
                     const float* __restrict__ segX, const float* __restrict__ segF,
                     f16* __restrict__ AC) {
  int b = blockIdx.x, s = blockIdx.y, i = threadIdx.x;
  float xm = xmean_p[0];
  float xl = 0.f;
  const float* sF = segF + ((size_t)(b * I_ + i)) * 8;
  const float* sX = segX + ((size_t)(b * I_ + i)) * 8;
  for (int p = 0; p < s; ++p) { if (sF[p] > 0.f) xl = sX[p]; }
  const float* xr = X + ((size_t)(b * I_ + i)) * T_;
  const float* mr = M + ((size_t)(b * I_ + i)) * T_;
  for (int tl = 0; tl < 128; ++tl) {
    int t = s * 128 + tl;
    float x = xr[t], m = mr[t];
    float gx = Gx[((size_t)(b * T_ + t)) * I_ + i];
    if (m > 0.f) xl = x;  // x_last updated BEFORE imputation (ref order)
    float x1 = m * x + (1.f - m) * (gx * x + (1.f - gx) * xm);
    float x2 = m * x1 + (1.f - m) * (gx * xl + (1.f - gx) * xm);
    size_t o = ((size_t)(b * T_ + t)) * 256;
    AC[o + i] = (f16)x2;
    AC[o + 128 + i] = (f16)m;
  }
}

// ---------- K4: recurrence, quad-shuffle reduction, 2 barriers/step ----------
// R16 post-mortem: 4 barriers + LDS partial round-trips = critical path (4660
// cyc/step at VALUBusy 10%). This version: each row's four 64-k slices live in
// one lane QUAD (lane = 4*rloc + ks); partials combine via 2x shfl_xor
// in-register; the ks==0 lane owns the row state (hd, z) and updates directly.
// Barriers: B1 (rhdh visible), B2 (hdh visible). z-dots run in P1 (depend only
// on hdh), consumed at update in P2.
// Weights: wr 64 u32 + wh 56 u32 regs; Whh sliver (k 56..64 of slice) + Whz
// fully in LDS [c][tid] uint4 (conflict-free). ~150 reg demand vs 128 cap ->
// small loop-invariant spill, acceptable.
__global__ __launch_bounds__(512, 2) void k_recur12(
    const f16* __restrict__ Gh, const f16* __restrict__ P,
    const uint32_t* __restrict__ blobR, const uint32_t* __restrict__ blobHrg,
    const uint32_t* __restrict__ blobZ4, const uint32_t* __restrict__ blobHl4,
    float* __restrict__ out) {
  __shared__ __align__(16) uint4 whzl[16 * 512];   // 131072 B
  __shared__ __align__(16) uint4 whhl[2 * 512];    //  16384 B
  __shared__ __align__(16) f16 hdh[256];
  __shared__ __align__(16) f16 rhdh[256];
  int tid = threadIdx.x;
  int b = blockIdx.x;
  int w = tid >> 6, l = tid & 63;
  int rloc = l >> 2, ks = l & 3;
  bool upd = (ks == 0);
  int row0 = w * 16 + rloc;          // task 0 row
  int row1 = row0 + 128;             // task 1 row

  #pragma unroll
  for (int i = 0; i < 16; ++i) whzl[i * 512 + tid] = ((const uint4*)blobZ4)[i * 512 + tid];
  #pragma unroll
  for (int i = 0; i < 2; ++i)  whhl[i * 512 + tid] = ((const uint4*)blobHl4)[i * 512 + tid];

  uint32_t wr[64], wh[56];
  #pragma unroll
  for (int c = 0; c < 64; ++c) wr[c] = blobR[c * 512 + tid];
  #pragma unroll
  for (int c = 0; c < 56; ++c) wh[c] = blobHrg[c * 512 + tid];

  const f16* gbase = Gh + (size_t)b * T_ * 256;
  const f16* pbase = P + (size_t)b * T_ * 768;
  float* outb = out + (size_t)b * T_ * 256;

  // init state (step 0): hd = gamma(0)*h0 = 0
  if (tid < 256) hdh[tid] = (f16)0.f;
  float hd0 = 0.f, hd1 = 0.f;
  float pr0 = (float)pbase[256 + row0];
  float pr1 = (float)pbase[256 + row1];
  float pz0 = 0.f, pz1 = 0.f, ph0 = 0.f, ph1 = 0.f, g0 = 0.f, g1 = 0.f;
  if (upd) {
    pz0 = (float)pbase[row0];        pz1 = (float)pbase[row1];
    ph0 = (float)pbase[512 + row0];  ph1 = (float)pbase[512 + row1];
    g0  = (float)gbase[256 + row0];  g1  = (float)gbase[256 + row1];
  }
  __syncthreads();

  for (int it = 0; it < T_; ++it) {
    // prefetch next-iter operands (consumed next iter; vmcnt never drained
    // by bar_lgkm, so latency spans the whole step)
    float pr0n = 0.f, pr1n = 0.f, pz0n = 0.f, pz1n = 0.f, ph0n = 0.f, ph1n = 0.f,
          g0n = 0.f, g1n = 0.f;
    if (it + 1 < T_) {
      const f16* pn = pbase + (size_t)(it + 1) * 768;
      pr0n = (float)pn[256 + row0];
      pr1n = (float)pn[256 + row1];
      if (upd) {
        pz0n = (float)pn[row0];       pz1n = (float)pn[row1];
        ph0n = (float)pn[512 + row0]; ph1n = (float)pn[512 + row1];
      }
    }
    if (upd && it + 2 < T_) {
      const f16* gn = gbase + (size_t)(it + 2) * 256;
      g0n = (float)gn[row0]; g1n = (float)gn[row1];
    }

    // P1: r-dots (regs) + z-dots (LDS), slices of rows row0,row1; quad-shfl
    const uint4* hd4 = (const uint4*)hdh;
    float r0a = 0.f, r0b = 0.f, r1a = 0.f, r1b = 0.f;
    float z0a = 0.f, z0b = 0.f, z1a = 0.f, z1b = 0.f;
    #pragma unroll
    for (int c4 = 0; c4 < 8; ++c4) {
      uint4 hv = hd4[ks * 8 + c4];
      r0a = fdot2_u(wr[c4 * 4 + 0], hv.x, r0a);
      r0b = fdot2_u(wr[c4 * 4 + 1], hv.y, r0b);
      r0a = fdot2_u(wr[c4 * 4 + 2], hv.z, r0a);
      r0b = fdot2_u(wr[c4 * 4 + 3], hv.w, r0b);
      r1a = fdot2_u(wr[32 + c4 * 4 + 0], hv.x, r1a);
      r1b = fdot2_u(wr[32 + c4 * 4 + 1], hv.y, r1b);
      r1a = fdot2_u(wr[32 + c4 * 4 + 2], hv.z, r1a);
      r1b = fdot2_u(wr[32 + c4 * 4 + 3], hv.w, r1b);
      uint4 zv0 = whzl[c4 * 512 + tid];
      z0a = fdot2_u(zv0.x, hv.x, z0a);
      z0b = fdot2_u(zv0.y, hv.y, z0b);
      z0a = fdot2_u(zv0.z, hv.z, z0a);
      z0b = fdot2_u(zv0.w, hv.w, z0b);
      uint4 zv1 = whzl[(8 + c4) * 512 + tid];
      z1a = fdot2_u(zv1.x, hv.x, z1a);
      z1b = fdot2_u(zv1.y, hv.y, z1b);
      z1a = fdot2_u(zv1.z, hv.z, z1a);
      z1b = fdot2_u(zv1.w, hv.w, z1b);
    }
    float racc0 = r0a + r0b, racc1 = r1a + r1b;
    float zacc0 = z0a + z0b, zacc1 = z1a + z1b;
    racc0 += __shfl_xor(racc0, 1); racc0 += __shfl_xor(racc0, 2);
    racc1 += __shfl_xor(racc1, 1); racc1 += __shfl_xor(racc1, 2);
    zacc0 += __shfl_xor(zacc0, 1); zacc0 += __shfl_xor(zacc0, 2);
    zacc1 += __shfl_xor(zacc1, 1); zacc1 += __shfl_xor(zacc1, 2);
    if (upd) {
      rhdh[row0] = (f16)(sigmoidf(racc0 + pr0) * hd0);
      rhdh[row1] = (f16)(sigmoidf(racc1 + pr1) * hd1);
    }
    bar_lgkm();  // B1: rhdh visible
    // P2: h-dots on rhdh (regs k<56 + LDS sliver k 56..64), quad-shfl, update
    const uint4* rh4 = (const uint4*)rhdh;
    float h0a = 0.f, h0b = 0.f, h1a = 0.f, h1b = 0.f;
    #pragma unroll
    for (int c4 = 0; c4 < 7; ++c4) {
      uint4 rv = rh4[ks * 8 + c4];
      h0a = fdot2_u(wh[c4 * 4 + 0], rv.x, h0a);
      h0b = fdot2_u(wh[c4 * 4 + 1], rv.y, h0b);
      h0a = fdot2_u(wh[c4 * 4 + 2], rv.z, h0a);
      h0b = fdot2_u(wh[c4 * 4 + 3], rv.w, h0b);
      h1a = fdot2_u(wh[28 + c4 * 4 + 0], rv.x, h1a);
      h1b = fdot2_u(wh[28 + c4 * 4 + 1], rv.y, h1b);
      h1a = fdot2_u(wh[28 + c4 * 4 + 2], rv.z, h1a);
      h1b = fdot2_u(wh[28 + c4 * 4 + 3], rv.w, h1b);
    }
    {
      uint4 rv = rh4[ks * 8 + 7];
      uint4 wv0 = whhl[0 * 512 + tid];
      h0a = fdot2_u(wv0.x, rv.x, h0a);
      h0b = fdot2_u(wv0.y, rv.y, h0b);
      h0a = fdot2_u(wv0.z, rv.z, h0a);
      h0b = fdot2_u(wv0.w, rv.w, h0b);
      uint4 wv1 = whhl[1 * 512 + tid];
      h1a = fdot2_u(wv1.x, rv.x, h1a);
      h1b = fdot2_u(wv1.y, rv.y, h1b);
      h1a = fdot2_u(wv1.z, rv.z, h1a);
      h1b = fdot2_u(wv1.w, rv.w, h1b);
    }
    float hacc0 = h0a + h0b, hacc1 = h1a + h1b;
    hacc0 += __shfl_xor(hacc0, 1); hacc0 += __shfl_xor(hacc0, 2);
    hacc1 += __shfl_xor(hacc1, 1); hacc1 += __shfl_xor(hacc1, 2);
    if (upd) {
      float z0v = sigmoidf(zacc0 + pz0);
      float z1v = sigmoidf(zacc1 + pz1);
      float ht0 = tanh_stable(hacc0 + ph0);
      float ht1 = tanh_stable(hacc1 + ph1);
      float hn0 = (1.f - z0v) * hd0 + z0v * ht0;
      float hn1 = (1.f - z1v) * hd1 + z1v * ht1;
      float* o = outb + (size_t)it * 256;
      o[row0] = hn0;
      o[row1] = hn1;
      hd0 = g0 * hn0;
      hd1 = g1 * hn1;
      hdh[row0] = (f16)hd0;
      hdh[row1] = (f16)hd1;
    }
    pr0 = pr0n; pr1 = pr1n; pz0 = pz0n; pz1 = pz1n;
    ph0 = ph0n; ph1 = ph1n; g0 = g0n; g1 = g1n;
    bar_lgkm();  // B2: hdh visible for next step
  }
}

// ---------- workspace layout ----------
static constexpr size_t OFF_P  = 0;                          // f16 [BT][768]  = 100663296 B
static constexpr size_t OFF_DT = 0;                          // f16 [BT][128]  (overlay; dead before K3)
static constexpr size_t OFF_GX = 100663296;                  // f32 [BT][128]  = 33554432
static constexpr size_t OFF_GH = OFF_GX + 33554432;          // f16 [BT][256]  = 33554432
static constexpr size_t OFF_AC = OFF_GH + 33554432;          // f16 [BT][256]  = 33554432
static constexpr size_t OFF_WG = OFF_AC + 33554432;          // f16 [384][128] = 98304
static constexpr size_t OFF_BG = OFF_WG + 98304;             // f32 [384]      = 1536
static constexpr size_t OFF_W3 = OFF_BG + 1536;              // f16 [768][256] = 393216
static constexpr size_t OFF_B3 = OFF_W3 + 393216;            // f32 [768]      = 3072
static constexpr size_t OFF_BR = OFF_B3 + 3072;              // u32 [64][512]  = 131072
static constexpr size_t OFF_BH = OFF_BR + 131072;            // u32 [56][512]  = 114688
static constexpr size_t OFF_BZ = OFF_BH + 114688;            // u32 [16*512*4] = 131072
static constexpr size_t OFF_BL = OFF_BZ + 131072;            // u32 [2*512*4]  = 16384
static constexpr size_t OFF_SX = OFF_BL + 16384;             // f32 [B][I][8]  = 262144
static constexpr size_t OFF_SF = OFF_SX + 262144;            // f32 [B][I][8]  = 262144
static constexpr size_t WS_TOTAL = OFF_SF + 262144;          // ~193.4 MiB

extern "C" void kernel_launch(void* const* d_in, const int* in_sizes, int n_in,
                              void* d_out, int out_size, void* d_ws, size_t ws_size,
                              hipStream_t stream) {
  const float* X    = (const float*)d_in[0];
  const float* Mask = (const float*)d_in[1];
  const float* Delta= (const float*)d_in[2];
  const float* xm   = (const float*)d_in[3];
  const float* Wdgx = (const float*)d_in[4];
  const float* bdgx = (const float*)d_in[5];
  const float* Wdgh = (const float*)d_in[6];
  const float* bdgh = (const float*)d_in[7];
  const float* Wxz  = (const float*)d_in[8];
  const float* Whz  = (const float*)d_in[9];
  const float* Wmz  = (const float*)d_in[10];
  const float* bmz  = (const float*)d_in[11];
  const float* Wxr  = (const float*)d_in[12];
  const float* Whr  = (const float*)d_in[13];
  const float* Wmr  = (const float*)d_in[14];
  const float* Wxh  = (const float*)d_in[15];
  const float* Whh  = (const float*)d_in[16];
  const float* Wmh  = (const float*)d_in[17];
  const float* bmh  = (const float*)d_in[18];
  float* out = (float*)d_out;   // f32 output (reference returns float32)
  char* ws = (char*)d_ws;
  if (ws_size < WS_TOTAL) return;  // insufficient scratch: bail cleanly

  f16*      Dt   = (f16*)(ws + OFF_DT);
  f16*      P    = (f16*)(ws + OFF_P);
  float*    Gx   = (float*)(ws + OFF_GX);
  f16*      Gh   = (f16*)(ws + OFF_GH);
  f16*      AC   = (f16*)(ws + OFF_AC);
  f16*      Wg   = (f16*)(ws + OFF_WG);
  float*    bg   = (float*)(ws + OFF_BG);
  f16*      W3   = (f16*)(ws + OFF_W3);
  float*    b3   = (float*)(ws + OFF_B3);
  uint32_t* blR  = (uint32_t*)(ws + OFF_BR);
  uint32_t* blH  = (uint32_t*)(ws + OFF_BH);
  uint32_t* blZ  = (uint32_t*)(ws + OFF_BZ);
  uint32_t* blL  = (uint32_t*)(ws + OFF_BL);
  float*    segX = (float*)(ws + OFF_SX);
  float*    segF = (float*)(ws + OFF_SF);

  k_prep<<<dim3(64), dim3(256), 0, stream>>>(Wdgx, bdgx, Wdgh, bdgh, Wxz, Whz, Wmz, bmz,
                                             Wxr, Whr, Wmr, Wxh, Whh, Wmh, bmh,
                                             Wg, bg, W3, b3, blR, blH, blZ, blL);
  k_transpose_d<<<dim3(16, 2, 64), dim3(64, 4), 0, stream>>>(Delta, Dt);
  k_gemm1<<<dim3(1024, 3), dim3(256), 0, stream>>>(Dt, Wg, bg, Gx, Gh);
  k_seg<<<dim3(64, 8), dim3(128), 0, stream>>>(X, Mask, segX, segF);
  k_x2<<<dim3(64, 8), dim3(128), 0, stream>>>(X, Mask, Gx, xm, segX, segF, AC);
  k_gemm3<<<dim3(1024, 6), dim3(256), 0, stream>>>(AC, W3, b3, P);
  k_recur12<<<dim3(64), dim3(512), 0, stream>>>(Gh, P, blR, blH, blZ, blL, out);
}

// Round 19
// 2547.579 us; speedup vs baseline: 1.1079x; 1.1079x over previous
//
#include <hip/hip_runtime.h>
#include <cstdint>
#include <cstddef>

typedef _Float16 f16;
typedef _Float16 f16x8 __attribute__((ext_vector_type(8)));
typedef _Float16 f16x2 __attribute__((ext_vector_type(2)));
typedef float f32x4 __attribute__((ext_vector_type(4)));

#define B_ 64
#define I_ 128
#define H_ 256
#define T_ 1024
#define BT_ (B_*T_)

// ---------- helpers ----------
__device__ __forceinline__ uint32_t pack2_f16(float a, float b) {
  union { f16 h; uint16_t u; } ua, ub;
  ua.h = (f16)a; ub.h = (f16)b;
  return ((uint32_t)ub.u << 16) | (uint32_t)ua.u;
}

__device__ __forceinline__ float fdot2_u(uint32_t w, uint32_t x, float acc) {
  union { uint32_t u; f16x2 h; } uw, ux;
  uw.u = w; ux.u = x;
  return __builtin_amdgcn_fdot2(uw.h, ux.h, acc, false);
}

__device__ __forceinline__ float tanh_stable(float s) {
  float a = fabsf(s);
  float e = __expf(-2.f * a);
  float t = (1.f - e) * __fdividef(1.f, 1.f + e);
  return s < 0.f ? -t : t;
}

__device__ __forceinline__ float sigmoidf(float s) {
  return __fdividef(1.f, 1.f + __expf(-s));
}

// MFMA fragment load (verified R3==R4)
__device__ __forceinline__ f16x8 load_frag(const f16* row, int k0, int g4) {
  union { uint32_t u[4]; f16x8 h; } r;
  const uint32_t* p0 = (const uint32_t*)(row + k0 + g4);
  const uint32_t* p1 = (const uint32_t*)(row + k0 + 16 + g4);
  r.u[0] = p0[0]; r.u[1] = p0[1];
  r.u[2] = p1[0]; r.u[3] = p1[1];
  return r.h;
}

// ---------- K0: transpose Delta [B,I,T] -> Dt f16 [B,T,I] ----------
__global__ void k_transpose_d(const float* __restrict__ D, f16* __restrict__ Dt) {
  __shared__ float tile[64][65];
  int t0 = blockIdx.x * 64, i0 = blockIdx.y * 64, b = blockIdx.z;
  int tx = threadIdx.x, ty = threadIdx.y;  // 64 x 4
  #pragma unroll
  for (int r = 0; r < 16; ++r) {
    int il = ty + r * 4;
    tile[il][tx] = D[((size_t)(b * I_ + i0 + il)) * T_ + t0 + tx];
  }
  __syncthreads();
  #pragma unroll
  for (int r = 0; r < 16; ++r) {
    int tl = ty + r * 4;
    Dt[((size_t)(b * T_ + t0 + tl)) * I_ + i0 + tx] = (f16)tile[tx][tl];
  }
}

// ---------- K_w: weight prep (layouts identical to R16) ----------
// Thread model (512 thr): ks=t>>7, rg=t&127, rows r0=2rg, r1=2rg+1,
// k-slice K=[64ks, 64ks+64).
// blobR   [c<64][t]:  c=rr*32+cc -> Whr[row rr][k=64ks+2cc] pair.
// blobHrg [c<56][t]:  c=p*28+cc  -> Whh[row p][k=64ks+2cc] (cc<28).
// blobZ4  [(c4<16)*512+t][q<4]: Whz; c4=rr*8+qq -> k=64ks+qq*8+2q.
// blobHl4 [(c4<2)*512+t][q<4]:  Whh sliver; c4=rr -> k=64ks+56+2q.
__global__ void k_prep(const float* __restrict__ Wdgx, const float* __restrict__ bdgx,
                       const float* __restrict__ Wdgh, const float* __restrict__ bdgh,
                       const float* __restrict__ Wxz, const float* __restrict__ Whz,
                       const float* __restrict__ Wmz, const float* __restrict__ bmz,
                       const float* __restrict__ Wxr, const float* __restrict__ Whr,
                       const float* __restrict__ Wmr,
                       const float* __restrict__ Wxh, const float* __restrict__ Whh,
                       const float* __restrict__ Wmh, const float* __restrict__ bmh,
                       f16* __restrict__ Wg, float* __restrict__ bg,
                       f16* __restrict__ W3, float* __restrict__ b3,
                       uint32_t* __restrict__ blobR, uint32_t* __restrict__ blobHrg,
                       uint32_t* __restrict__ blobZ4, uint32_t* __restrict__ blobHl4) {
  int tid = blockIdx.x * blockDim.x + threadIdx.x;
  int nth = gridDim.x * blockDim.x;
  for (int idx = tid; idx < 384 * 128; idx += nth) {
    int j = idx >> 7, k = idx & 127;
    float v = (j < 128) ? Wdgx[j * 128 + k] : Wdgh[(j - 128) * 128 + k];
    Wg[idx] = (f16)v;
  }
  for (int j = tid; j < 384; j += nth) bg[j] = (j < 128) ? bdgx[j] : bdgh[j - 128];
  for (int idx = tid; idx < 768 * 256; idx += nth) {
    int j = idx >> 8, c = idx & 255;
    const float* Wx = (j < 256) ? Wxz : ((j < 512) ? Wxr : Wxh);
    const float* Wm = (j < 256) ? Wmz : ((j < 512) ? Wmr : Wmh);
    int jj = j & 255;
    float v = (c < 128) ? Wx[jj * 128 + c] : Wm[jj * 128 + (c - 128)];
    W3[idx] = (f16)v;
  }
  for (int j = tid; j < 768; j += nth)
    b3[j] = (j < 256) ? bmz[j] : ((j < 512) ? 0.0f : bmh[j - 512]);
  // blobR
  for (int idx = tid; idx < 64 * 512; idx += nth) {
    int c = idx >> 9, t = idx & 511;
    int rr = c >> 5, cc = c & 31;
    int ks = t >> 7, rg = t & 127;
    int row = rg * 2 + rr;
    int k = ks * 64 + cc * 2;
    blobR[idx] = pack2_f16(Whr[row * 256 + k], Whr[row * 256 + k + 1]);
  }
  // blobHrg
  for (int idx = tid; idx < 56 * 512; idx += nth) {
    int c = idx >> 9, t = idx & 511;
    int rr = (c >= 28) ? 1 : 0, cc = c - rr * 28;
    int ks = t >> 7, rg = t & 127;
    int row = rg * 2 + rr;
    int k = ks * 64 + cc * 2;
    blobHrg[idx] = pack2_f16(Whh[row * 256 + k], Whh[row * 256 + k + 1]);
  }
  // blobZ4
  for (int idx = tid; idx < 16 * 512 * 4; idx += nth) {
    int q = idx & 3, r = idx >> 2;
    int t = r & 511, c4 = r >> 9;
    int rr = c4 >> 3, qq = c4 & 7;
    int ks = t >> 7, rg = t & 127;
    int row = rg * 2 + rr;
    int k = ks * 64 + qq * 8 + q * 2;
    blobZ4[idx] = pack2_f16(Whz[row * 256 + k], Whz[row * 256 + k + 1]);
  }
  // blobHl4
  for (int idx = tid; idx < 2 * 512 * 4; idx += nth) {
    int q = idx & 3, r = idx >> 2;
    int t = r & 511, rr = r >> 9;
    int ks = t >> 7, rg = t & 127;
    int row = rg * 2 + rr;
    int k = ks * 64 + 56 + q * 2;
    blobHl4[idx] = pack2_f16(Whh[row * 256 + k], Whh[row * 256 + k + 1]);
  }
}

// ---------- K1 (MFMA): Gx/Gh = exp(-relu(Dt @ Wg^T + bg)) ----------
__global__ __launch_bounds__(256) void k_gemm1(const f16* __restrict__ A,
                                               const f16* __restrict__ W,
                                               const float* __restrict__ bias,
                                               float* __restrict__ Gx,
                                               f16* __restrict__ Gh) {
  __shared__ __align__(16) f16 As[64][136];
  __shared__ __align__(16) f16 Ws[128][136];
  int m0 = blockIdx.x * 64, n0 = blockIdx.y * 128;
  int tid = threadIdx.x;
  {
    int r = tid >> 2, sgm = tid & 3;
    const uint4* src = (const uint4*)(A + (size_t)(m0 + r) * 128 + sgm * 32);
    uint4* dst = (uint4*)(&As[r][sgm * 32]);
    #pragma unroll
    for (int q = 0; q < 4; ++q) dst[q] = src[q];
  }
  {
    int r = tid >> 1, hf = tid & 1;
    const uint4* src = (const uint4*)(W + (size_t)(n0 + r) * 128 + hf * 64);
    uint4* dst = (uint4*)(&Ws[r][hf * 64]);
    #pragma unroll
    for (int q = 0; q < 8; ++q) dst[q] = src[q];
  }
  __syncthreads();
  int w = tid >> 6, l = tid & 63;
  int lr = l & 15, g4 = (l >> 4) * 4;
  f32x4 acc[8] = {};
  #pragma unroll
  for (int kk = 0; kk < 4; ++kk) {
    int k0 = kk * 32;
    f16x8 a = load_frag(&As[w * 16 + lr][0], k0, g4);
    #pragma unroll
    for (int nt = 0; nt < 8; ++nt) {
      f16x8 bf = load_frag(&Ws[nt * 16 + lr][0], k0, g4);
      acc[nt] = __builtin_amdgcn_mfma_f32_16x16x32_f16(a, bf, acc[nt], 0, 0, 0);
    }
  }
  int row4 = (l >> 4) * 4;
  #pragma unroll
  for (int nt = 0; nt < 8; ++nt) {
    int n = n0 + nt * 16 + lr;
    float bv = bias[n];
    #pragma unroll
    for (int reg = 0; reg < 4; ++reg) {
      int m = m0 + w * 16 + row4 + reg;
      float s = acc[nt][reg] + bv;
      float g = __expf(-fmaxf(s, 0.0f));
      if (n < 128) Gx[(size_t)m * 128 + n] = g;
      else         Gh[(size_t)m * 256 + (n - 128)] = (f16)g;
    }
  }
}

// ---------- K3 (MFMA): P = AC @ W3^T + b3 (f16 out) ----------
__global__ __launch_bounds__(256) void k_gemm3(const f16* __restrict__ A,
                                               const f16* __restrict__ W,
                                               const float* __restrict__ bias,
                                               f16* __restrict__ P) {
  __shared__ __align__(16) f16 As[64][136];
  __shared__ __align__(16) f16 Ws[128][136];
  int m0 = blockIdx.x * 64, n0 = blockIdx.y * 128;
  int tid = threadIdx.x;
  int w = tid >> 6, l = tid & 63, lr = l & 15, g4 = (l >> 4) * 4;
  f32x4 acc[8] = {};
  for (int kh = 0; kh < 2; ++kh) {
    {
      int r = tid >> 2, sgm = tid & 3;
      const uint4* src = (const uint4*)(A + (size_t)(m0 + r) * 256 + kh * 128 + sgm * 32);
      uint4* dst = (uint4*)(&As[r][sgm * 32]);
      #pragma unroll
      for (int q = 0; q < 4; ++q) dst[q] = src[q];
    }
    {
      int r = tid >> 1, hf = tid & 1;
      const uint4* src = (const uint4*)(W + (size_t)(n0 + r) * 256 + kh * 128 + hf * 64);
      uint4* dst = (uint4*)(&Ws[r][hf * 64]);
      #pragma unroll
      for (int q = 0; q < 8; ++q) dst[q] = src[q];
    }
    __syncthreads();
    #pragma unroll
    for (int kk = 0; kk < 4; ++kk) {
      int k0 = kk * 32;
      f16x8 a = load_frag(&As[w * 16 + lr][0], k0, g4);
      #pragma unroll
      for (int nt = 0; nt < 8; ++nt) {
        f16x8 bf = load_frag(&Ws[nt * 16 + lr][0], k0, g4);
        acc[nt] = __builtin_amdgcn_mfma_f32_16x16x32_f16(a, bf, acc[nt], 0, 0, 0);
      }
    }
    __syncthreads();
  }
  int row4 = (l >> 4) * 4;
  #pragma unroll
  for (int nt = 0; nt < 8; ++nt) {
    int n = n0 + nt * 16 + lr;
    float bv = bias[n];
    #pragma unroll
    for (int reg = 0; reg < 4; ++reg) {
      int m = m0 + w * 16 + row4 + reg;
      P[(size_t)m * 768 + n] = (f16)(acc[nt][reg] + bv);
    }
  }
}

// ---------- K2a: per-segment last-observation summaries ----------
__global__ void k_seg(const float* __restrict__ X, const float* __restrict__ M,
                      float* __restrict__ segX, float* __restrict__ segF) {
  int b = blockIdx.x, s = blockIdx.y, i = threadIdx.x;
  const float* xr = X + ((size_t)(b * I_ + i)) * T_ + s * 128;
  const float* mr = M + ((size_t)(b * I_ + i)) * T_ + s * 128;
  float last = 0.f, seen = 0.f;
  for (int t = 0; t < 128; ++t) {
    float m = mr[t];
    float x = xr[t];
    if (m > 0.f) { last = x; seen = 1.f; }
  }
  segX[((size_t)(b * I_ + i)) * 8 + s] = last;
  segF[((size_t)(b * I_ + i)) * 8 + s] = seen;
}

// ---------- K2b: x_last + double imputation -> AC f16 [BT][256] = [x2 | m] ----------
__global__ void k_x2(const float* __restrict__ X, const float* __restrict__ M,
                     const float* __restrict__ Gx, const float* __restrict__ xmean_p,
                     const float* __restrict__ segX, const float* __restrict__ segF,
                     f16* __restrict__ AC) {
  int b = blockIdx.x, s = blockIdx.y, i = threadIdx.x;
  float xm = xmean_p[0];
  float xl = 0.f;
  const float* sF = segF + ((size_t)(b * I_ + i)) * 8;
  const float* sX = segX + ((size_t)(b * I_ + i)) * 8;
  for (int p = 0; p < s; ++p) { if (sF[p] > 0.f) xl = sX[p]; }
  const float* xr = X + ((size_t)(b * I_ + i)) * T_;
  const float* mr = M + ((size_t)(b * I_ + i)) * T_;
  for (int tl = 0; tl < 128; ++tl) {
    int t = s * 128 + tl;
    float x = xr[t], m = mr[t];
    float gx = Gx[((size_t)(b * T_ + t)) * I_ + i];
    if (m > 0.f) xl = x;  // x_last updated BEFORE imputation (ref order)
    float x1 = m * x + (1.f - m) * (gx * x + (1.f - gx) * xm);
    float x2 = m * x1 + (1.f - m) * (gx * xl + (1.f - gx) * xm);
    size_t o = ((size_t)(b * T_ + t)) * 256;
    AC[o + i] = (f16)x2;
    AC[o + 128 + i] = (f16)m;
  }
}

// ---------- K4: recurrence = R16 structure + two diagnosed fixes ----------
// Fix 1 (prefetch placement): R16 issued the 6 P/Gh prefetch loads right
//   BEFORE B1 -> __syncthreads' vmcnt(0) drained them EXPOSED every step.
//   Now issued after B2 (consumed next step) -> drained at B3 under P3 cover.
// Fix 2 (tail-streaming): pinned wR 64->56, wH 56->16; the tails are read
//   per-step from the existing blob layouts in global (L2-hot, coalesced
//   dword loads, addresses repeat every step). Batches: wRt(8) at loop top,
//   wHt[0..20) after B1, wHt[20..40) after B2. Cuts register demand
//   (R16 spilled ~43 u32; now ~15-20).
// Everything else identical to R16 (best measured: 1992 us).
__global__ __launch_bounds__(512, 2) void k_recur13(
    const f16* __restrict__ Gh, const f16* __restrict__ P,
    const uint32_t* __restrict__ blobR, const uint32_t* __restrict__ blobHrg,
    const uint32_t* __restrict__ blobZ4, const uint32_t* __restrict__ blobHl4,
    float* __restrict__ out) {
  __shared__ __align__(16) uint4 whzl[16 * 512];   // 131072 B
  __shared__ __align__(16) uint4 whhl[2 * 512];    //  16384 B
  __shared__ __align__(16) float partR[4][256];    //   4096 B (reused for h)
  __shared__ __align__(16) float partZ[4][256];    //   4096 B
  __shared__ __align__(16) f16 hdh[256];
  __shared__ __align__(16) f16 rhdh[256];
  int tid = threadIdx.x;
  int b = blockIdx.x;
  int ks = tid >> 7, rg = tid & 127;
  bool lo = tid < 256;

  #pragma unroll
  for (int i = 0; i < 16; ++i) whzl[i * 512 + tid] = ((const uint4*)blobZ4)[i * 512 + tid];
  #pragma unroll
  for (int i = 0; i < 2; ++i)  whhl[i * 512 + tid] = ((const uint4*)blobHl4)[i * 512 + tid];

  uint32_t wR[56], wH[16];
  #pragma unroll
  for (int c = 0; c < 56; ++c) wR[c] = blobR[c * 512 + tid];
  #pragma unroll
  for (int c = 0; c < 16; ++c) wH[c] = blobHrg[c * 512 + tid];
  const uint32_t* gRt = blobR + 56 * 512 + tid;     // 8 tail dwords, stride 512
  const uint32_t* gHt = blobHrg + 16 * 512 + tid;   // 40 tail dwords, stride 512

  const f16* gbase = Gh + (size_t)b * T_ * 256;
  const f16* pbase = P + (size_t)b * T_ * 768;
  const f16* ghp = gbase + 2 * 256 + tid;        // gamma(it+2), lo only
  const f16* pzp = pbase + 768 + tid;            // P[it+1][tid], all 512
  const f16* php = pbase + 768 + 512 + tid;      // P[it+1][512+tid], lo only
  float* outp = out + (size_t)b * T_ * 256 + tid;

  float hd_own = 0.f, z_reg = 0.f;
  float pzr_c = (float)pbase[tid];               // P[0][tid] (z for lo, r for hi)
  float ph_c  = lo ? (float)pbase[512 + tid] : 0.f;
  float gh_u  = lo ? (float)gbase[256 + tid] : 0.f;   // gamma(1)
  if (lo) hdh[tid] = (f16)0.f;                   // hd(0) = gamma(0)*h0 = 0
  __syncthreads();

  for (int it = 0; it < T_; ++it) {
    // stream wR tail (consumed at P1 c4>=6, ~200+ cyc later; L2-hot)
    uint32_t wRt[8];
    #pragma unroll
    for (int i = 0; i < 8; ++i) wRt[i] = gRt[i * 512];

    // P1: r-dots (regs+tail) + z-dots (LDS whzl), rows 2rg,2rg+1, k-slice ks
    {
      const uint4* hd4 = (const uint4*)hdh;
      float r0 = 0.f, r1 = 0.f, z0 = 0.f, z1 = 0.f;
      #pragma unroll
      for (int c4 = 0; c4 < 8; ++c4) {
        uint4 hv = hd4[ks * 8 + c4];               // wave-uniform broadcast
        r0 = fdot2_u(wR[c4 * 4 + 0], hv.x, r0);
        r0 = fdot2_u(wR[c4 * 4 + 1], hv.y, r0);
        r0 = fdot2_u(wR[c4 * 4 + 2], hv.z, r0);
        r0 = fdot2_u(wR[c4 * 4 + 3], hv.w, r0);
        if (c4 < 6) {
          r1 = fdot2_u(wR[32 + c4 * 4 + 0], hv.x, r1);
          r1 = fdot2_u(wR[32 + c4 * 4 + 1], hv.y, r1);
          r1 = fdot2_u(wR[32 + c4 * 4 + 2], hv.z, r1);
          r1 = fdot2_u(wR[32 + c4 * 4 + 3], hv.w, r1);
        } else {
          r1 = fdot2_u(wRt[(c4 - 6) * 4 + 0], hv.x, r1);
          r1 = fdot2_u(wRt[(c4 - 6) * 4 + 1], hv.y, r1);
          r1 = fdot2_u(wRt[(c4 - 6) * 4 + 2], hv.z, r1);
          r1 = fdot2_u(wRt[(c4 - 6) * 4 + 3], hv.w, r1);
        }
        uint4 wz0 = whzl[c4 * 512 + tid];          // consecutive per lane
        z0 = fdot2_u(wz0.x, hv.x, z0);
        z0 = fdot2_u(wz0.y, hv.y, z0);
        z0 = fdot2_u(wz0.z, hv.z, z0);
        z0 = fdot2_u(wz0.w, hv.w, z0);
        uint4 wz1 = whzl[(8 + c4) * 512 + tid];
        z1 = fdot2_u(wz1.x, hv.x, z1);
        z1 = fdot2_u(wz1.y, hv.y, z1);
        z1 = fdot2_u(wz1.z, hv.z, z1);
        z1 = fdot2_u(wz1.w, hv.w, z1);
        if (c4 & 1) __builtin_amdgcn_sched_barrier(0);
      }
      partR[ks][rg * 2 + 0] = r0;
      partR[ks][rg * 2 + 1] = r1;
      partZ[ks][rg * 2 + 0] = z0;
      partZ[ks][rg * 2 + 1] = z1;
    }
    __syncthreads();  // B1
    // stream wHt first batch (consumed in P3, ~400+ cyc later)
    uint32_t wHt[40];
    #pragma unroll
    for (int i = 0; i < 20; ++i) wHt[i] = gHt[i * 512];
    // P2: lo finish-z (kept in reg); hi finish-r -> rhdh
    if (lo) {
      z_reg = sigmoidf(pzr_c + partZ[0][tid] + partZ[1][tid] + partZ[2][tid] + partZ[3][tid]);
    } else {
      int row = tid - 256;
      float s = pzr_c + partR[0][row] + partR[1][row] + partR[2][row] + partR[3][row];
      rhdh[row] = (f16)(sigmoidf(s) * (float)hdh[row]);
    }
    __syncthreads();  // B2
    // stream wHt second batch + issue NEXT-iter P/Gh prefetch (Fix 1: drained
    // at B3 under P3's compute cover, not exposed at B1 like R16)
    #pragma unroll
    for (int i = 20; i < 40; ++i) wHt[i] = gHt[i * 512];
    float pzr_n = 0.f, ph_n = 0.f, gh_n = 0.f;
    if (it + 1 < T_) {
      pzr_n = (float)pzp[0];
      if (lo) ph_n = (float)php[0];
    }
    if (lo && it + 2 < T_) gh_n = (float)ghp[0];
    pzp += 768; php += 768; ghp += 256;
    // P3: h-dots on rhdh (wH regs k<16, wHt stream k16..56, whhl sliver) -> partR
    {
      const uint4* rh4 = (const uint4*)rhdh;
      float h0 = 0.f, h1 = 0.f;
      #pragma unroll
      for (int c4 = 0; c4 < 7; ++c4) {
        uint4 rv = rh4[ks * 8 + c4];
        if (c4 < 4) {
          h0 = fdot2_u(wH[c4 * 4 + 0], rv.x, h0);
          h0 = fdot2_u(wH[c4 * 4 + 1], rv.y, h0);
          h0 = fdot2_u(wH[c4 * 4 + 2], rv.z, h0);
          h0 = fdot2_u(wH[c4 * 4 + 3], rv.w, h0);
        } else {
          h0 = fdot2_u(wHt[(c4 - 4) * 4 + 0], rv.x, h0);
          h0 = fdot2_u(wHt[(c4 - 4) * 4 + 1], rv.y, h0);
          h0 = fdot2_u(wHt[(c4 - 4) * 4 + 2], rv.z, h0);
          h0 = fdot2_u(wHt[(c4 - 4) * 4 + 3], rv.w, h0);
        }
        h1 = fdot2_u(wHt[12 + c4 * 4 + 0], rv.x, h1);
        h1 = fdot2_u(wHt[12 + c4 * 4 + 1], rv.y, h1);
        h1 = fdot2_u(wHt[12 + c4 * 4 + 2], rv.z, h1);
        h1 = fdot2_u(wHt[12 + c4 * 4 + 3], rv.w, h1);
        if (c4 & 1) __builtin_amdgcn_sched_barrier(0);
      }
      {
        uint4 rv = rh4[ks * 8 + 7];
        uint4 wh0 = whhl[0 * 512 + tid];
        h0 = fdot2_u(wh0.x, rv.x, h0);
        h0 = fdot2_u(wh0.y, rv.y, h0);
        h0 = fdot2_u(wh0.z, rv.z, h0);
        h0 = fdot2_u(wh0.w, rv.w, h0);
        uint4 wh1 = whhl[1 * 512 + tid];
        h1 = fdot2_u(wh1.x, rv.x, h1);
        h1 = fdot2_u(wh1.y, rv.y, h1);
        h1 = fdot2_u(wh1.z, rv.z, h1);
        h1 = fdot2_u(wh1.w, rv.w, h1);
      }
      partR[ks][rg * 2 + 0] = h0;
      partR[ks][rg * 2 + 1] = h1;
    }
    __syncthreads();  // B3
    // P4: lo finish-h, update, store, write hd(it+1)
    if (lo) {
      float s2 = ph_c + partR[0][tid] + partR[1][tid] + partR[2][tid] + partR[3][tid];
      float ht = tanh_stable(s2);
      float hnew = (1.f - z_reg) * hd_own + z_reg * ht;
      outp[0] = hnew;
      outp += 256;
      hd_own = gh_u * hnew;
      hdh[tid] = (f16)hd_own;
    }
    pzr_c = pzr_n; ph_c = ph_n; gh_u = gh_n;
    __syncthreads();  // B4 (hdh write vs next-iter P1/P2 readers)
  }
}

// ---------- workspace layout ----------
static constexpr size_t OFF_P  = 0;                          // f16 [BT][768]  = 100663296 B
static constexpr size_t OFF_DT = 0;                          // f16 [BT][128]  (overlay; dead before K3)
static constexpr size_t OFF_GX = 100663296;                  // f32 [BT][128]  = 33554432
static constexpr size_t OFF_GH = OFF_GX + 33554432;          // f16 [BT][256]  = 33554432
static constexpr size_t OFF_AC = OFF_GH + 33554432;          // f16 [BT][256]  = 33554432
static constexpr size_t OFF_WG = OFF_AC + 33554432;          // f16 [384][128] = 98304
static constexpr size_t OFF_BG = OFF_WG + 98304;             // f32 [384]      = 1536
static constexpr size_t OFF_W3 = OFF_BG + 1536;              // f16 [768][256] = 393216
static constexpr size_t OFF_B3 = OFF_W3 + 393216;            // f32 [768]      = 3072
static constexpr size_t OFF_BR = OFF_B3 + 3072;              // u32 [64][512]  = 131072
static constexpr size_t OFF_BH = OFF_BR + 131072;            // u32 [56][512]  = 114688
static constexpr size_t OFF_BZ = OFF_BH + 114688;            // u32 [16*512*4] = 131072
static constexpr size_t OFF_BL = OFF_BZ + 131072;            // u32 [2*512*4]  = 16384
static constexpr size_t OFF_SX = OFF_BL + 16384;             // f32 [B][I][8]  = 262144
static constexpr size_t OFF_SF = OFF_SX + 262144;            // f32 [B][I][8]  = 262144
static constexpr size_t WS_TOTAL = OFF_SF + 262144;          // ~193.4 MiB

extern "C" void kernel_launch(void* const* d_in, const int* in_sizes, int n_in,
                              void* d_out, int out_size, void* d_ws, size_t ws_size,
                              hipStream_t stream) {
  const float* X    = (const float*)d_in[0];
  const float* Mask = (const float*)d_in[1];
  const float* Delta= (const float*)d_in[2];
  const float* xm   = (const float*)d_in[3];
  const float* Wdgx = (const float*)d_in[4];
  const float* bdgx = (const float*)d_in[5];
  const float* Wdgh = (const float*)d_in[6];
  const float* bdgh = (const float*)d_in[7];
  const float* Wxz  = (const float*)d_in[8];
  const float* Whz  = (const float*)d_in[9];
  const float* Wmz  = (const float*)d_in[10];
  const float* bmz  = (const float*)d_in[11];
  const float* Wxr  = (const float*)d_in[12];
  const float* Whr  = (const float*)d_in[13];
  const float* Wmr  = (const float*)d_in[14];
  const float* Wxh  = (const float*)d_in[15];
  const float* Whh  = (const float*)d_in[16];
  const float* Wmh  = (const float*)d_in[17];
  const float* bmh  = (const float*)d_in[18];
  float* out = (float*)d_out;   // f32 output (reference returns float32)
  char* ws = (char*)d_ws;
  if (ws_size < WS_TOTAL) return;  // insufficient scratch: bail cleanly

  f16*      Dt   = (f16*)(ws + OFF_DT);
  f16*      P    = (f16*)(ws + OFF_P);
  float*    Gx   = (float*)(ws + OFF_GX);
  f16*      Gh   = (f16*)(ws + OFF_GH);
  f16*      AC   = (f16*)(ws + OFF_AC);
  f16*      Wg   = (f16*)(ws + OFF_WG);
  float*    bg   = (float*)(ws + OFF_BG);
  f16*      W3   = (f16*)(ws + OFF_W3);
  float*    b3   = (float*)(ws + OFF_B3);
  uint32_t* blR  = (uint32_t*)(ws + OFF_BR);
  uint32_t* blH  = (uint32_t*)(ws + OFF_BH);
  uint32_t* blZ  = (uint32_t*)(ws + OFF_BZ);
  uint32_t* blL  = (uint32_t*)(ws + OFF_BL);
  float*    segX = (float*)(ws + OFF_SX);
  float*    segF = (float*)(ws + OFF_SF);

  k_prep<<<dim3(64), dim3(256), 0, stream>>>(Wdgx, bdgx, Wdgh, bdgh, Wxz, Whz, Wmz, bmz,
                                             Wxr, Whr, Wmr, Wxh, Whh, Wmh, bmh,
                                             Wg, bg, W3, b3, blR, blH, blZ, blL);
  k_transpose_d<<<dim3(16, 2, 64), dim3(64, 4), 0, stream>>>(Delta, Dt);
  k_gemm1<<<dim3(1024, 3), dim3(256), 0, stream>>>(Dt, Wg, bg, Gx, Gh);
  k_seg<<<dim3(64, 8), dim3(128), 0, stream>>>(X, Mask, segX, segF);
  k_x2<<<dim3(64, 8), dim3(128), 0, stream>>>(X, Mask, Gx, xm, segX, segF, AC);
  k_gemm3<<<dim3(1024, 6), dim3(256), 0, stream>>>(AC, W3, b3, P);
  k_recur13<<<dim3(64), dim3(512), 0, stream>>>(Gh, P, blR, blH, blZ, blL, out);
}

// Round 20
// 2189.781 us; speedup vs baseline: 1.2889x; 1.1634x over previous
//
#include <hip/hip_runtime.h>
#include <cstdint>
#include <cstddef>

typedef _Float16 f16;
typedef _Float16 f16x8 __attribute__((ext_vector_type(8)));
typedef _Float16 f16x2 __attribute__((ext_vector_type(2)));
typedef float f32x4 __attribute__((ext_vector_type(4)));

#define B_ 64
#define I_ 128
#define H_ 256
#define T_ 1024
#define BT_ (B_*T_)

// ---------- helpers ----------
__device__ __forceinline__ uint32_t pack2_f16(float a, float b) {
  union { f16 h; uint16_t u; } ua, ub;
  ua.h = (f16)a; ub.h = (f16)b;
  return ((uint32_t)ub.u << 16) | (uint32_t)ua.u;
}

__device__ __forceinline__ float fdot2_u(uint32_t w, uint32_t x, float acc) {
  union { uint32_t u; f16x2 h; } uw, ux;
  uw.u = w; ux.u = x;
  return __builtin_amdgcn_fdot2(uw.h, ux.h, acc, false);
}

__device__ __forceinline__ float tanh_stable(float s) {
  float a = fabsf(s);
  float e = __expf(-2.f * a);
  float t = (1.f - e) * __fdividef(1.f, 1.f + e);
  return s < 0.f ? -t : t;
}

__device__ __forceinline__ float sigmoidf(float s) {
  return __fdividef(1.f, 1.f + __expf(-s));
}

// MFMA fragment load (verified R3==R4)
__device__ __forceinline__ f16x8 load_frag(const f16* row, int k0, int g4) {
  union { uint32_t u[4]; f16x8 h; } r;
  const uint32_t* p0 = (const uint32_t*)(row + k0 + g4);
  const uint32_t* p1 = (const uint32_t*)(row + k0 + 16 + g4);
  r.u[0] = p0[0]; r.u[1] = p0[1];
  r.u[2] = p1[0]; r.u[3] = p1[1];
  return r.h;
}

// ---------- K0: transpose Delta [B,I,T] -> Dt f16 [B,T,I] ----------
__global__ void k_transpose_d(const float* __restrict__ D, f16* __restrict__ Dt) {
  __shared__ float tile[64][65];
  int t0 = blockIdx.x * 64, i0 = blockIdx.y * 64, b = blockIdx.z;
  int tx = threadIdx.x, ty = threadIdx.y;  // 64 x 4
  #pragma unroll
  for (int r = 0; r < 16; ++r) {
    int il = ty + r * 4;
    tile[il][tx] = D[((size_t)(b * I_ + i0 + il)) * T_ + t0 + tx];
  }
  __syncthreads();
  #pragma unroll
  for (int r = 0; r < 16; ++r) {
    int tl = ty + r * 4;
    Dt[((size_t)(b * T_ + t0 + tl)) * I_ + i0 + tx] = (f16)tile[tx][tl];
  }
}

// ---------- K_w: weight prep ----------
// Thread model for k_recur10 (512 thr): ks=t>>7, rg=t&127, rows r0=2rg, r1=2rg+1,
// k-slice K=[64ks, 64ks+64).
// blobR   [c<64][t]:  c=rr*32+cc -> Whr[row rr][k=64ks+2cc] pair.      (regs)
// blobHrg [c<56][t]:  c=p*28+cc  -> Whh[row p][k=64ks+2cc] (cc<28).    (regs)
// blobZ4  [(c4<16)*512+t][q<4]: Whz; c4=rr*8+qq -> k=64ks+qq*8+2q.     (LDS)
// blobHl4 [(c4<2)*512+t][q<4]:  Whh sliver; c4=rr -> k=64ks+56+2q.     (LDS)
__global__ void k_prep(const float* __restrict__ Wdgx, const float* __restrict__ bdgx,
                       const float* __restrict__ Wdgh, const float* __restrict__ bdgh,
                       const float* __restrict__ Wxz, const float* __restrict__ Whz,
                       const float* __restrict__ Wmz, const float* __restrict__ bmz,
                       const float* __restrict__ Wxr, const float* __restrict__ Whr,
                       const float* __restrict__ Wmr,
                       const float* __restrict__ Wxh, const float* __restrict__ Whh,
                       const float* __restrict__ Wmh, const float* __restrict__ bmh,
                       f16* __restrict__ Wg, float* __restrict__ bg,
                       f16* __restrict__ W3, float* __restrict__ b3,
                       uint32_t* __restrict__ blobR, uint32_t* __restrict__ blobHrg,
                       uint32_t* __restrict__ blobZ4, uint32_t* __restrict__ blobHl4) {
  int tid = blockIdx.x * blockDim.x + threadIdx.x;
  int nth = gridDim.x * blockDim.x;
  // Wg [384][128]
  for (int idx = tid; idx < 384 * 128; idx += nth) {
    int j = idx >> 7, k = idx & 127;
    float v = (j < 128) ? Wdgx[j * 128 + k] : Wdgh[(j - 128) * 128 + k];
    Wg[idx] = (f16)v;
  }
  for (int j = tid; j < 384; j += nth) bg[j] = (j < 128) ? bdgx[j] : bdgh[j - 128];
  // W3 [768][256]
  for (int idx = tid; idx < 768 * 256; idx += nth) {
    int j = idx >> 8, c = idx & 255;
    const float* Wx = (j < 256) ? Wxz : ((j < 512) ? Wxr : Wxh);
    const float* Wm = (j < 256) ? Wmz : ((j < 512) ? Wmr : Wmh);
    int jj = j & 255;
    float v = (c < 128) ? Wx[jj * 128 + c] : Wm[jj * 128 + (c - 128)];
    W3[idx] = (f16)v;
  }
  for (int j = tid; j < 768; j += nth)
    b3[j] = (j < 256) ? bmz[j] : ((j < 512) ? 0.0f : bmh[j - 512]);
  // blobR
  for (int idx = tid; idx < 64 * 512; idx += nth) {
    int c = idx >> 9, t = idx & 511;
    int rr = c >> 5, cc = c & 31;
    int ks = t >> 7, rg = t & 127;
    int row = rg * 2 + rr;
    int k = ks * 64 + cc * 2;
    blobR[idx] = pack2_f16(Whr[row * 256 + k], Whr[row * 256 + k + 1]);
  }
  // blobHrg
  for (int idx = tid; idx < 56 * 512; idx += nth) {
    int c = idx >> 9, t = idx & 511;
    int rr = (c >= 28) ? 1 : 0, cc = c - rr * 28;
    int ks = t >> 7, rg = t & 127;
    int row = rg * 2 + rr;
    int k = ks * 64 + cc * 2;
    blobHrg[idx] = pack2_f16(Whh[row * 256 + k], Whh[row * 256 + k + 1]);
  }
  // blobZ4
  for (int idx = tid; idx < 16 * 512 * 4; idx += nth) {
    int q = idx & 3, r = idx >> 2;
    int t = r & 511, c4 = r >> 9;
    int rr = c4 >> 3, qq = c4 & 7;
    int ks = t >> 7, rg = t & 127;
    int row = rg * 2 + rr;
    int k = ks * 64 + qq * 8 + q * 2;
    blobZ4[idx] = pack2_f16(Whz[row * 256 + k], Whz[row * 256 + k + 1]);
  }
  // blobHl4
  for (int idx = tid; idx < 2 * 512 * 4; idx += nth) {
    int q = idx & 3, r = idx >> 2;
    int t = r & 511, rr = r >> 9;
    int ks = t >> 7, rg = t & 127;
    int row = rg * 2 + rr;
    int k = ks * 64 + 56 + q * 2;
    blobHl4[idx] = pack2_f16(Whh[row * 256 + k], Whh[row * 256 + k + 1]);
  }
}

// ---------- K1 (MFMA): Gx/Gh = exp(-relu(Dt @ Wg^T + bg)) ----------
__global__ __launch_bounds__(256) void k_gemm1(const f16* __restrict__ A,
                                               const f16* __restrict__ W,
                                               const float* __restrict__ bias,
                                               float* __restrict__ Gx,
                                               f16* __restrict__ Gh) {
  __shared__ __align__(16) f16 As[64][136];
  __shared__ __align__(16) f16 Ws[128][136];
  int m0 = blockIdx.x * 64, n0 = blockIdx.y * 128;
  int tid = threadIdx.x;
  {
    int r = tid >> 2, sgm = tid & 3;
    const uint4* src = (const uint4*)(A + (size_t)(m0 + r) * 128 + sgm * 32);
    uint4* dst = (uint4*)(&As[r][sgm * 32]);
    #pragma unroll
    for (int q = 0; q < 4; ++q) dst[q] = src[q];
  }
  {
    int r = tid >> 1, hf = tid & 1;
    const uint4* src = (const uint4*)(W + (size_t)(n0 + r) * 128 + hf * 64);
    uint4* dst = (uint4*)(&Ws[r][hf * 64]);
    #pragma unroll
    for (int q = 0; q < 8; ++q) dst[q] = src[q];
  }
  __syncthreads();
  int w = tid >> 6, l = tid & 63;
  int lr = l & 15, g4 = (l >> 4) * 4;
  f32x4 acc[8] = {};
  #pragma unroll
  for (int kk = 0; kk < 4; ++kk) {
    int k0 = kk * 32;
    f16x8 a = load_frag(&As[w * 16 + lr][0], k0, g4);
    #pragma unroll
    for (int nt = 0; nt < 8; ++nt) {
      f16x8 bf = load_frag(&Ws[nt * 16 + lr][0], k0, g4);
      acc[nt] = __builtin_amdgcn_mfma_f32_16x16x32_f16(a, bf, acc[nt], 0, 0, 0);
    }
  }
  int row4 = (l >> 4) * 4;
  #pragma unroll
  for (int nt = 0; nt < 8; ++nt) {
    int n = n0 + nt * 16 + lr;
    float bv = bias[n];
    #pragma unroll
    for (int reg = 0; reg < 4; ++reg) {
      int m = m0 + w * 16 + row4 + reg;
      float s = acc[nt][reg] + bv;
      float g = __expf(-fmaxf(s, 0.0f));
      if (n < 128) Gx[(size_t)m * 128 + n] = g;
      else         Gh[(size_t)m * 256 + (n - 128)] = (f16)g;
    }
  }
}

// ---------- K3 (MFMA): P = AC @ W3^T + b3 (f16 out) ----------
__global__ __launch_bounds__(256) void k_gemm3(const f16* __restrict__ A,
                                               const f16* __restrict__ W,
                                               const float* __restrict__ bias,
                                               f16* __restrict__ P) {
  __shared__ __align__(16) f16 As[64][136];
  __shared__ __align__(16) f16 Ws[128][136];
  int m0 = blockIdx.x * 64, n0 = blockIdx.y * 128;
  int tid = threadIdx.x;
  int w = tid >> 6, l = tid & 63, lr = l & 15, g4 = (l >> 4) * 4;
  f32x4 acc[8] = {};
  for (int kh = 0; kh < 2; ++kh) {
    {
      int r = tid >> 2, sgm = tid & 3;
      const uint4* src = (const uint4*)(A + (size_t)(m0 + r) * 256 + kh * 128 + sgm * 32);
      uint4* dst = (uint4*)(&As[r][sgm * 32]);
      #pragma unroll
      for (int q = 0; q < 4; ++q) dst[q] = src[q];
    }
    {
      int r = tid >> 1, hf = tid & 1;
      const uint4* src = (const uint4*)(W + (size_t)(n0 + r) * 256 + kh * 128 + hf * 64);
      uint4* dst = (uint4*)(&Ws[r][hf * 64]);
      #pragma unroll
      for (int q = 0; q < 8; ++q) dst[q] = src[q];
    }
    __syncthreads();
    #pragma unroll
    for (int kk = 0; kk < 4; ++kk) {
      int k0 = kk * 32;
      f16x8 a = load_frag(&As[w * 16 + lr][0], k0, g4);
      #pragma unroll
      for (int nt = 0; nt < 8; ++nt) {
        f16x8 bf = load_frag(&Ws[nt * 16 + lr][0], k0, g4);
        acc[nt] = __builtin_amdgcn_mfma_f32_16x16x32_f16(a, bf, acc[nt], 0, 0, 0);
      }
    }
    __syncthreads();
  }
  int row4 = (l >> 4) * 4;
  #pragma unroll
  for (int nt = 0; nt < 8; ++nt) {
    int n = n0 + nt * 16 + lr;
    float bv = bias[n];
    #pragma unroll
    for (int reg = 0; reg < 4; ++reg) {
      int m = m0 + w * 16 + row4 + reg;
      P[(size_t)m * 768 + n] = (f16)(acc[nt][reg] + bv);
    }
  }
}

// ---------- K2a: per-segment last-observation summaries ----------
__global__ void k_seg(const float* __restrict__ X, const float* __restrict__ M,
                      float* __restrict__ segX, float* __restrict__ segF) {
  int b = blockIdx.x, s = blockIdx.y, i = threadIdx.x;
  const float* xr = X + ((size_t)(b * I_ + i)) * T_ + s * 128;
  const float* mr = M + ((size_t)(b * I_ + i)) * T_ + s * 128;
  float last = 0.f, seen = 0.f;
  for (int t = 0; t < 128; ++t) {
    float m = mr[t];
    float x = xr[t];
    if (m > 0.f) { last = x; seen = 1.f; }
  }
  segX[((size_t)(b * I_ + i)) * 8 + s] = last;
  segF[((size_t)(b * I_ + i)) * 8 + s] = seen;
}

// ---------- K2b: x_last + double imputation -> AC f16 [BT][256] = [x2 | m] ----------
__global__ void k_x2(const float* __restrict__ X, const float* __restrict__ M,
                     const float* __restrict__ Gx, const float* __restrict__ xmean_p,
                     const float* __restrict__ segX, const float* __restrict__ segF,
                     f16* __restrict__ AC) {
  int b = blockIdx.x, s = blockIdx.y, i = threadIdx.x;
  float xm = xmean_p[0];
  float xl = 0.f;
  const float* sF = segF + ((size_t)(b * I_ + i)) * 8;
  const float* sX = segX + ((size_t)(b * I_ + i)) * 8;
  for (int p = 0; p < s; ++p) { if (sF[p] > 0.f) xl = sX[p]; }
  const float* xr = X + ((size_t)(b * I_ + i)) * T_;
  const float* mr = M + ((size_t)(b * I_ + i)) * T_;
  for (int tl = 0; tl < 128; ++tl) {
    int t = s * 128 + tl;
    float x = xr[t], m = mr[t];
    float gx = Gx[((size_t)(b * T_ + t)) * I_ + i];
    if (m > 0.f) xl = x;  // x_last updated BEFORE imputation (ref order)
    float x1 = m * x + (1.f - m) * (gx * x + (1.f - gx) * xm);
    float x2 = m * x1 + (1.f - m) * (gx * xl + (1.f - gx) * xm);
    size_t o = ((size_t)(b * T_ + t)) * 256;
    AC[o + i] = (f16)x2;
    AC[o + 128 + i] = (f16)m;
  }
}

// ---------- K4: recurrence, 512 threads, three-way weight residency ----------
// BEST MEASURED CONFIG (R16: 1992 us). Reverted verbatim after R17-R19
// variants (raw barriers / quad-shuffle / tail-streaming) all regressed.
// Capacity split:
//   regs  : Whr 64 u32 + Whh 56 u32 = 120/thread
//   LDS   : Whz full (128 KB, [c4][tid] uint4, conflict-free) + Whh sliver
//           (16 KB) + partR/partZ + hdh/rhdh ~= 153 KB
// 2 waves/SIMD; 4 phases, 4 barriers.
__global__ __launch_bounds__(512, 2) void k_recur10(
    const f16* __restrict__ Gh, const f16* __restrict__ P,
    const uint32_t* __restrict__ blobR, const uint32_t* __restrict__ blobHrg,
    const uint32_t* __restrict__ blobZ4, const uint32_t* __restrict__ blobHl4,
    float* __restrict__ out) {
  __shared__ __align__(16) uint4 whzl[16 * 512];   // 131072 B
  __shared__ __align__(16) uint4 whhl[2 * 512];    //  16384 B
  __shared__ __align__(16) float partR[4][256];    //   4096 B (reused for h-dots)
  __shared__ __align__(16) float partZ[4][256];    //   4096 B
  __shared__ __align__(16) f16 hdh[256];
  __shared__ __align__(16) f16 rhdh[256];
  int tid = threadIdx.x;
  int b = blockIdx.x;
  int ks = tid >> 7, rg = tid & 127;
  bool lo = tid < 256;

  // stage LDS weights (coalesced uint4)
  #pragma unroll
  for (int i = 0; i < 16; ++i) whzl[i * 512 + tid] = ((const uint4*)blobZ4)[i * 512 + tid];
  #pragma unroll
  for (int i = 0; i < 2; ++i)  whhl[i * 512 + tid] = ((const uint4*)blobHl4)[i * 512 + tid];

  uint32_t wR[64], wH[56];
  #pragma unroll
  for (int c = 0; c < 64; ++c) wR[c] = blobR[c * 512 + tid];
  #pragma unroll
  for (int c = 0; c < 56; ++c) wH[c] = blobHrg[c * 512 + tid];

  const f16* gbase = Gh + (size_t)b * T_ * 256;
  const f16* pbase = P + (size_t)b * T_ * 768;
  const f16* ghp = gbase + 2 * 256 + tid;        // gamma(it+2), lo only
  const f16* pzp = pbase + 768 + tid;            // P[it+1][tid], all 512
  const f16* php = pbase + 768 + 512 + tid;      // P[it+1][512+tid], lo only
  float* outp = out + (size_t)b * T_ * 256 + tid;

  float hd_own = 0.f, z_reg = 0.f;
  float pzr_c = (float)pbase[tid];               // P[0][tid] (z for lo, r for hi)
  float ph_c  = lo ? (float)pbase[512 + tid] : 0.f;
  float gh_u  = lo ? (float)gbase[256 + tid] : 0.f;   // gamma(1)
  if (lo) hdh[tid] = (f16)0.f;                   // hd(0) = gamma(0)*h0 = 0
  __syncthreads();

  for (int it = 0; it < T_; ++it) {
    // P1: r-dots (regs) + z-dots (LDS whzl), rows 2rg,2rg+1, k-slice ks
    {
      const uint4* hd4 = (const uint4*)hdh;
      float r0 = 0.f, r1 = 0.f, z0 = 0.f, z1 = 0.f;
      #pragma unroll
      for (int c4 = 0; c4 < 8; ++c4) {
        uint4 hv = hd4[ks * 8 + c4];               // wave-uniform broadcast
        r0 = fdot2_u(wR[c4 * 4 + 0], hv.x, r0);
        r0 = fdot2_u(wR[c4 * 4 + 1], hv.y, r0);
        r0 = fdot2_u(wR[c4 * 4 + 2], hv.z, r0);
        r0 = fdot2_u(wR[c4 * 4 + 3], hv.w, r0);
        r1 = fdot2_u(wR[32 + c4 * 4 + 0], hv.x, r1);
        r1 = fdot2_u(wR[32 + c4 * 4 + 1], hv.y, r1);
        r1 = fdot2_u(wR[32 + c4 * 4 + 2], hv.z, r1);
        r1 = fdot2_u(wR[32 + c4 * 4 + 3], hv.w, r1);
        uint4 wz0 = whzl[c4 * 512 + tid];          // consecutive per lane
        z0 = fdot2_u(wz0.x, hv.x, z0);
        z0 = fdot2_u(wz0.y, hv.y, z0);
        z0 = fdot2_u(wz0.z, hv.z, z0);
        z0 = fdot2_u(wz0.w, hv.w, z0);
        uint4 wz1 = whzl[(8 + c4) * 512 + tid];
        z1 = fdot2_u(wz1.x, hv.x, z1);
        z1 = fdot2_u(wz1.y, hv.y, z1);
        z1 = fdot2_u(wz1.z, hv.z, z1);
        z1 = fdot2_u(wz1.w, hv.w, z1);
        if (c4 & 1) __builtin_amdgcn_sched_barrier(0);
      }
      partR[ks][rg * 2 + 0] = r0;
      partR[ks][rg * 2 + 1] = r1;
      partZ[ks][rg * 2 + 0] = z0;
      partZ[ks][rg * 2 + 1] = z1;
    }
    // prefetch next-iter operands (hidden under P2/P3)
    float pzr_n = 0.f, ph_n = 0.f, gh_n = 0.f;
    if (it + 1 < T_) {
      pzr_n = (float)pzp[0];
      if (lo) ph_n = (float)php[0];
    }
    if (lo && it + 2 < T_) gh_n = (float)ghp[0];
    pzp += 768; php += 768; ghp += 256;
    __syncthreads();  // B1
    // P2: lo finish-z (kept in reg); hi finish-r -> rhdh
    if (lo) {
      z_reg = sigmoidf(pzr_c + partZ[0][tid] + partZ[1][tid] + partZ[2][tid] + partZ[3][tid]);
    } else {
      int row = tid - 256;
      float s = pzr_c + partR[0][row] + partR[1][row] + partR[2][row] + partR[3][row];
      rhdh[row] = (f16)(sigmoidf(s) * (float)hdh[row]);
    }
    __syncthreads();  // B2
    // P3: h-dots on rhdh (wH regs k<56, whhl sliver k 56..64) -> partR (reuse)
    {
      const uint4* rh4 = (const uint4*)rhdh;
      float h0 = 0.f, h1 = 0.f;
      #pragma unroll
      for (int c4 = 0; c4 < 7; ++c4) {
        uint4 rv = rh4[ks * 8 + c4];
        h0 = fdot2_u(wH[c4 * 4 + 0], rv.x, h0);
        h0 = fdot2_u(wH[c4 * 4 + 1], rv.y, h0);
        h0 = fdot2_u(wH[c4 * 4 + 2], rv.z, h0);
        h0 = fdot2_u(wH[c4 * 4 + 3], rv.w, h0);
        h1 = fdot2_u(wH[28 + c4 * 4 + 0], rv.x, h1);
        h1 = fdot2_u(wH[28 + c4 * 4 + 1], rv.y, h1);
        h1 = fdot2_u(wH[28 + c4 * 4 + 2], rv.z, h1);
        h1 = fdot2_u(wH[28 + c4 * 4 + 3], rv.w, h1);
        if (c4 & 1) __builtin_amdgcn_sched_barrier(0);
      }
      {
        uint4 rv = rh4[ks * 8 + 7];
        uint4 wh0 = whhl[0 * 512 + tid];
        h0 = fdot2_u(wh0.x, rv.x, h0);
        h0 = fdot2_u(wh0.y, rv.y, h0);
        h0 = fdot2_u(wh0.z, rv.z, h0);
        h0 = fdot2_u(wh0.w, rv.w, h0);
        uint4 wh1 = whhl[1 * 512 + tid];
        h1 = fdot2_u(wh1.x, rv.x, h1);
        h1 = fdot2_u(wh1.y, rv.y, h1);
        h1 = fdot2_u(wh1.z, rv.z, h1);
        h1 = fdot2_u(wh1.w, rv.w, h1);
      }
      partR[ks][rg * 2 + 0] = h0;
      partR[ks][rg * 2 + 1] = h1;
    }
    __syncthreads();  // B3
    // P4: lo finish-h, update, store, write hd(it+1)
    if (lo) {
      float s2 = ph_c + partR[0][tid] + partR[1][tid] + partR[2][tid] + partR[3][tid];
      float ht = tanh_stable(s2);
      float hnew = (1.f - z_reg) * hd_own + z_reg * ht;
      outp[0] = hnew;
      outp += 256;
      hd_own = gh_u * hnew;
      hdh[tid] = (f16)hd_own;
    }
    pzr_c = pzr_n; ph_c = ph_n; gh_u = gh_n;
    __syncthreads();  // B4 (hdh write vs next-iter P1/P2 readers)
  }
}

// ---------- workspace layout ----------
static constexpr size_t OFF_P  = 0;                          // f16 [BT][768]  = 100663296 B
static constexpr size_t OFF_DT = 0;                          // f16 [BT][128]  (overlay; dead before K3)
static constexpr size_t OFF_GX = 100663296;                  // f32 [BT][128]  = 33554432
static constexpr size_t OFF_GH = OFF_GX + 33554432;          // f16 [BT][256]  = 33554432
static constexpr size_t OFF_AC = OFF_GH + 33554432;          // f16 [BT][256]  = 33554432
static constexpr size_t OFF_WG = OFF_AC + 33554432;          // f16 [384][128] = 98304
static constexpr size_t OFF_BG = OFF_WG + 98304;             // f32 [384]      = 1536
static constexpr size_t OFF_W3 = OFF_BG + 1536;              // f16 [768][256] = 393216
static constexpr size_t OFF_B3 = OFF_W3 + 393216;            // f32 [768]      = 3072
static constexpr size_t OFF_BR = OFF_B3 + 3072;              // u32 [64][512]  = 131072
static constexpr size_t OFF_BH = OFF_BR + 131072;            // u32 [56][512]  = 114688
static constexpr size_t OFF_BZ = OFF_BH + 114688;            // u32 [16*512*4] = 131072
static constexpr size_t OFF_BL = OFF_BZ + 131072;            // u32 [2*512*4]  = 16384
static constexpr size_t OFF_SX = OFF_BL + 16384;             // f32 [B][I][8]  = 262144
static constexpr size_t OFF_SF = OFF_SX + 262144;            // f32 [B][I][8]  = 262144
static constexpr size_t WS_TOTAL = OFF_SF + 262144;          // ~193.4 MiB

extern "C" void kernel_launch(void* const* d_in, const int* in_sizes, int n_in,
                              void* d_out, int out_size, void* d_ws, size_t ws_size,
                              hipStream_t stream) {
  const float* X    = (const float*)d_in[0];
  const float* Mask = (const float*)d_in[1];
  const float* Delta= (const float*)d_in[2];
  const float* xm   = (const float*)d_in[3];
  const float* Wdgx = (const float*)d_in[4];
  const float* bdgx = (const float*)d_in[5];
  const float* Wdgh = (const float*)d_in[6];
  const float* bdgh = (const float*)d_in[7];
  const float* Wxz  = (const float*)d_in[8];
  const float* Whz  = (const float*)d_in[9];
  const float* Wmz  = (const float*)d_in[10];
  const float* bmz  = (const float*)d_in[11];
  const float* Wxr  = (const float*)d_in[12];
  const float* Whr  = (const float*)d_in[13];
  const float* Wmr  = (const float*)d_in[14];
  const float* Wxh  = (const float*)d_in[15];
  const float* Whh  = (const float*)d_in[16];
  const float* Wmh  = (const float*)d_in[17];
  const float* bmh  = (const float*)d_in[18];
  float* out = (float*)d_out;   // f32 output (reference returns float32)
  char* ws = (char*)d_ws;
  if (ws_size < WS_TOTAL) return;  // insufficient scratch: bail cleanly

  f16*      Dt   = (f16*)(ws + OFF_DT);
  f16*      P    = (f16*)(ws + OFF_P);
  float*    Gx   = (float*)(ws + OFF_GX);
  f16*      Gh   = (f16*)(ws + OFF_GH);
  f16*      AC   = (f16*)(ws + OFF_AC);
  f16*      Wg   = (f16*)(ws + OFF_WG);
  float*    bg   = (float*)(ws + OFF_BG);
  f16*      W3   = (f16*)(ws + OFF_W3);
  float*    b3   = (float*)(ws + OFF_B3);
  uint32_t* blR  = (uint32_t*)(ws + OFF_BR);
  uint32_t* blH  = (uint32_t*)(ws + OFF_BH);
  uint32_t* blZ  = (uint32_t*)(ws + OFF_BZ);
  uint32_t* blL  = (uint32_t*)(ws + OFF_BL);
  float*    segX = (float*)(ws + OFF_SX);
  float*    segF = (float*)(ws + OFF_SF);

  k_prep<<<dim3(64), dim3(256), 0, stream>>>(Wdgx, bdgx, Wdgh, bdgh, Wxz, Whz, Wmz, bmz,
                                             Wxr, Whr, Wmr, Wxh, Whh, Wmh, bmh,
                                             Wg, bg, W3, b3, blR, blH, blZ, blL);
  k_transpose_d<<<dim3(16, 2, 64), dim3(64, 4), 0, stream>>>(Delta, Dt);
  k_gemm1<<<dim3(1024, 3), dim3(256), 0, stream>>>(Dt, Wg, bg, Gx, Gh);
  k_seg<<<dim3(64, 8), dim3(128), 0, stream>>>(X, Mask, segX, segF);
  k_x2<<<dim3(64, 8), dim3(128), 0, stream>>>(X, Mask, Gx, xm, segX, segF, AC);
  k_gemm3<<<dim3(1024, 6), dim3(256), 0, stream>>>(AC, W3, b3, P);
  k_recur10<<<dim3(64), dim3(512), 0, stream>>>(Gh, P, blR, blH, blZ, blL, out);
}